// Round 1
// baseline (945.489 us; speedup 1.0000x reference)
//
#include <hip/hip_runtime.h>
#include <stdint.h>

// CodebookLayer (VQ snap): logits = x @ cb^T, argmax over 8192 codes, gather rows.
// Strategy: fp16 MFMA approximate logits (x_h · (c_h + c_l), err std ~0.009 vs
// top-2 gap mean ~8.7) + per-chunk top-2 candidates + exact fp64 recheck for
// any candidate within EPS of the max, then gather. Argmax must match np's fp32
// argmax exactly (one flip => absmax ~5 >> 0.108 threshold).

#define T_TOKENS 16384
#define N_CODES  8192
#define DIM      1024
#define BM 128
#define BN 128
#define BK 32
#define NBLK (N_CODES / BN)   // 64 code chunks
#define KITERS (DIM / BK)     // 32
#define EPS 0.15f

typedef _Float16 half8  __attribute__((ext_vector_type(8)));
typedef _Float16 half4v __attribute__((ext_vector_type(4)));
typedef float    f32x4  __attribute__((ext_vector_type(4)));

// async global->LDS, 16B per lane; LDS dest = wave-uniform base + lane*16
#define GLD16(gp, lp) \
  __builtin_amdgcn_global_load_lds((__attribute__((address_space(1))) void*)(gp), \
                                   (__attribute__((address_space(3))) void*)(lp), 16, 0, 0)

// ---------------------------------------------------------------- split kernels
__global__ __launch_bounds__(256) void vq_split_hi(const float* __restrict__ in,
                                                   _Float16* __restrict__ hi) {
  const size_t i = ((size_t)blockIdx.x * 256 + threadIdx.x) * 4;
  const float4 v = *(const float4*)(in + i);
  half4v h = {(_Float16)v.x, (_Float16)v.y, (_Float16)v.z, (_Float16)v.w};
  *(half4v*)(hi + i) = h;
}

__global__ __launch_bounds__(256) void vq_split_hilo(const float* __restrict__ in,
                                                     _Float16* __restrict__ hi,
                                                     _Float16* __restrict__ lo) {
  const size_t i = ((size_t)blockIdx.x * 256 + threadIdx.x) * 4;
  const float4 v = *(const float4*)(in + i);
  half4v h = {(_Float16)v.x, (_Float16)v.y, (_Float16)v.z, (_Float16)v.w};
  half4v l = {(_Float16)(v.x - (float)h.x), (_Float16)(v.y - (float)h.y),
              (_Float16)(v.z - (float)h.z), (_Float16)(v.w - (float)h.w)};
  *(half4v*)(hi + i) = h;
  *(half4v*)(lo + i) = l;
}

// ---------------------------------------------------------------- GEMM + top-2
__global__ __launch_bounds__(256) void vq_gemm_top2(
    const _Float16* __restrict__ xh,   // [T][D]
    const _Float16* __restrict__ ch,   // [C][D]
    const _Float16* __restrict__ cl,   // [C][D]
    float* __restrict__ pval,          // [T][NBLK][2]
    int*   __restrict__ pidx)          // [T][NBLK][2]
{
  __shared__ _Float16 As [BM * BK];    // 8KB
  __shared__ _Float16 Bhs[BN * BK];    // 8KB
  __shared__ _Float16 Bls[BN * BK];    // 8KB
  __shared__ float mv1[BM][2]; __shared__ float mv2[BM][2];
  __shared__ int   mi1[BM][2]; __shared__ int   mi2[BM][2];

  const int t    = threadIdx.x;
  const int wave = t >> 6;
  const int lane = t & 63;
  const int l15  = lane & 15;
  const int quad = lane >> 4;
  const int mb   = blockIdx.y * BM;    // token base
  const int nb   = blockIdx.x * BN;    // code base
  const int wm   = (wave >> 1) * 64;   // wave row base within tile
  const int wn   = (wave & 1) * 64;    // wave col base within tile

  // staging chunk mapping: chunk c (16B) -> row c>>2, k-col (c&3)*8
  const int c0 = t, c1 = t + 256;
  const int r0 = c0 >> 2, kc0 = (c0 & 3) * 8;
  const int r1 = c1 >> 2, kc1 = (c1 & 3) * 8;

  const _Float16* ax0 = xh + (size_t)(mb + r0) * DIM + kc0;
  const _Float16* ax1 = xh + (size_t)(mb + r1) * DIM + kc1;
  const _Float16* bh0 = ch + (size_t)(nb + r0) * DIM + kc0;
  const _Float16* bh1 = ch + (size_t)(nb + r1) * DIM + kc1;
  const _Float16* bl0 = cl + (size_t)(nb + r0) * DIM + kc0;
  const _Float16* bl1 = cl + (size_t)(nb + r1) * DIM + kc1;

  f32x4 acc[4][4];
#pragma unroll
  for (int i = 0; i < 4; ++i)
#pragma unroll
    for (int j = 0; j < 4; ++j)
      acc[i][j] = (f32x4){0.f, 0.f, 0.f, 0.f};

  for (int kt = 0; kt < KITERS; ++kt) {
    GLD16(ax0, &As [c0 * 8]);
    GLD16(ax1, &As [c1 * 8]);
    GLD16(bh0, &Bhs[c0 * 8]);
    GLD16(bh1, &Bhs[c1 * 8]);
    GLD16(bl0, &Bls[c0 * 8]);
    GLD16(bl1, &Bls[c1 * 8]);
    ax0 += BK; ax1 += BK; bh0 += BK; bh1 += BK; bl0 += BK; bl1 += BK;
    __syncthreads();   // drains vmcnt before barrier (compiler-inserted)

    half8 a[4], bh[4], bl[4];
#pragma unroll
    for (int s = 0; s < 4; ++s) {
      a[s]  = *(const half8*)&As [(wm + s * 16 + l15) * BK + quad * 8];
      bh[s] = *(const half8*)&Bhs[(wn + s * 16 + l15) * BK + quad * 8];
      bl[s] = *(const half8*)&Bls[(wn + s * 16 + l15) * BK + quad * 8];
    }
#pragma unroll
    for (int i = 0; i < 4; ++i)
#pragma unroll
      for (int j = 0; j < 4; ++j) {
        acc[i][j] = __builtin_amdgcn_mfma_f32_16x16x32_f16(a[i], bh[j], acc[i][j], 0, 0, 0);
        acc[i][j] = __builtin_amdgcn_mfma_f32_16x16x32_f16(a[i], bl[j], acc[i][j], 0, 0, 0);
      }
    __syncthreads();
  }

  // Epilogue: per-row top-2 over this block's 128 codes.
  // C/D layout: acc[i][j][r] = logits[wm + i*16 + quad*4 + r][wn + j*16 + l15]
#pragma unroll
  for (int i = 0; i < 4; ++i) {
#pragma unroll
    for (int r = 0; r < 4; ++r) {
      float v1 = -1e30f, v2 = -1e30f; int i1 = -1, i2 = -1;
#pragma unroll
      for (int j = 0; j < 4; ++j) {
        const float v = acc[i][j][r];
        const int idx = nb + wn + j * 16 + l15;
        if (v > v1) { v2 = v1; i2 = i1; v1 = v; i1 = idx; }
        else if (v > v2) { v2 = v; i2 = idx; }
      }
      // butterfly over the 16 lanes (low 4 lane bits) sharing this row
#pragma unroll
      for (int m = 1; m <= 8; m <<= 1) {
        const float bv1 = __shfl_xor(v1, m, 64);
        const int   bi1 = __shfl_xor(i1, m, 64);
        const float bv2 = __shfl_xor(v2, m, 64);
        const int   bi2 = __shfl_xor(i2, m, 64);
        if (bv1 > v1) {
          const float nv2 = (bv2 > v1) ? bv2 : v1;
          const int   ni2 = (bv2 > v1) ? bi2 : i1;
          v1 = bv1; i1 = bi1; v2 = nv2; i2 = ni2;
        } else if (bv1 > v2) { v2 = bv1; i2 = bi1; }
      }
      if (l15 == 0) {
        const int row = wm + i * 16 + quad * 4 + r;   // 0..127
        mv1[row][wave & 1] = v1; mi1[row][wave & 1] = i1;
        mv2[row][wave & 1] = v2; mi2[row][wave & 1] = i2;
      }
    }
  }
  __syncthreads();
  if (t < BM) {
    float v1 = mv1[t][0]; int i1 = mi1[t][0];
    float v2 = mv2[t][0]; int i2 = mi2[t][0];
    const float bv1 = mv1[t][1]; const int bi1 = mi1[t][1];
    const float bv2 = mv2[t][1]; const int bi2 = mi2[t][1];
    if (bv1 > v1) {
      const float nv2 = (bv2 > v1) ? bv2 : v1;
      const int   ni2 = (bv2 > v1) ? bi2 : i1;
      v1 = bv1; i1 = bi1; v2 = nv2; i2 = ni2;
    } else if (bv1 > v2) { v2 = bv1; i2 = bi1; }
    const size_t o = ((size_t)(mb + t) * NBLK + blockIdx.x) * 2;
    pval[o] = v1; pval[o + 1] = v2;
    pidx[o] = i1; pidx[o + 1] = i2;
  }
}

// ------------------------------------------------------- reduce + fp64 recheck
__global__ __launch_bounds__(128) void vq_reduce_phase2(
    const float* __restrict__ pval, const int* __restrict__ pidx,
    const float* __restrict__ x, const float* __restrict__ cb,
    int* __restrict__ fidx)
{
  __shared__ float  sv[2 * NBLK];
  __shared__ int    si[2 * NBLK];
  __shared__ int    scand[8];
  __shared__ int    scnt;
  __shared__ double red[128];
  __shared__ double sbest;
  __shared__ int    sbesti;

  const int tkn = blockIdx.x;
  const int t   = threadIdx.x;   // 128
  sv[t] = pval[(size_t)tkn * (2 * NBLK) + t];
  si[t] = pidx[(size_t)tkn * (2 * NBLK) + t];
  __syncthreads();
  if (t == 0) {
    float m = -1e30f;
    for (int e = 0; e < 2 * NBLK; ++e) m = fmaxf(m, sv[e]);
    int cnt = 0;
    for (int e = 0; e < 2 * NBLK && cnt < 8; ++e)
      if (sv[e] >= m - EPS) scand[cnt++] = si[e];
    scnt = cnt;
    sbest = -1e300; sbesti = N_CODES;
  }
  __syncthreads();
  const int cnt = scnt;
  if (cnt == 1) {            // uniform across block
    if (t == 0) fidx[tkn] = scand[0];
    return;
  }
  for (int ci = 0; ci < cnt; ++ci) {
    const int code = scand[ci];
    const float* xr = x + (size_t)tkn * DIM;
    const float* cr = cb + (size_t)code * DIM;
    double s = 0.0;
    for (int d = t; d < DIM; d += 128) s += (double)xr[d] * (double)cr[d];
    red[t] = s;
    __syncthreads();
    for (int off = 64; off > 0; off >>= 1) {
      if (t < off) red[t] += red[t + off];
      __syncthreads();
    }
    if (t == 0) {
      const double v = red[0];
      if (v > sbest || (v == sbest && code < sbesti)) { sbest = v; sbesti = code; }
    }
    __syncthreads();
  }
  if (t == 0) fidx[tkn] = sbesti;
}

// ---------------------------------------------------------------------- gather
__global__ __launch_bounds__(256) void vq_gather(const float* __restrict__ cb,
                                                 const int* __restrict__ fidx,
                                                 float* __restrict__ out) {
  const int tkn  = blockIdx.x;
  const int code = fidx[tkn];
  const float4* src = (const float4*)(cb + (size_t)code * DIM);
  float4*       dst = (float4*)(out + (size_t)tkn * DIM);
  dst[threadIdx.x] = src[threadIdx.x];   // 256 * 16B = 4KB row
}

// ------------------------------------------------- fallback (ws too small)
__global__ __launch_bounds__(256) void vq_naive(const float* __restrict__ x,
                                                const float* __restrict__ cb,
                                                float* __restrict__ out) {
  __shared__ float xs[DIM];
  __shared__ float bv[256];
  __shared__ int   bix[256];
  const int tkn = blockIdx.x;
  const int t = threadIdx.x;
  for (int d = t; d < DIM; d += 256) xs[d] = x[(size_t)tkn * DIM + d];
  __syncthreads();
  float best = -1e30f; int bi = N_CODES;
  for (int c = t; c < N_CODES; c += 256) {
    const float* cr = cb + (size_t)c * DIM;
    float s = 0.f;
    for (int d = 0; d < DIM; ++d) s += xs[d] * cr[d];
    if (s > best || (s == best && c < bi)) { best = s; bi = c; }
  }
  bv[t] = best; bix[t] = bi;
  __syncthreads();
  for (int off = 128; off > 0; off >>= 1) {
    if (t < off) {
      if (bv[t + off] > bv[t] || (bv[t + off] == bv[t] && bix[t + off] < bix[t])) {
        bv[t] = bv[t + off]; bix[t] = bix[t + off];
      }
    }
    __syncthreads();
  }
  const int code = bix[0];
  for (int d = t; d < DIM; d += 256)
    out[(size_t)tkn * DIM + d] = cb[(size_t)code * DIM + d];
}

// ---------------------------------------------------------------------- launch
extern "C" void kernel_launch(void* const* d_in, const int* in_sizes, int n_in,
                              void* d_out, int out_size, void* d_ws, size_t ws_size,
                              hipStream_t stream) {
  const float* x  = (const float*)d_in[0];   // [16384][1024]
  const float* cb = (const float*)d_in[1];   // [8192][1024]
  float* out = (float*)d_out;

  const size_t MB = 1024 * 1024;
  const size_t need = 48 * MB + 64 * 1024;
  if (ws_size >= need) {
    char* w = (char*)d_ws;
    _Float16* ch   = (_Float16*)(w);             // 16MB
    _Float16* cl   = (_Float16*)(w + 16 * MB);   // 16MB
    float*    pval = (float*)   (w + 32 * MB);   // 8MB
    int*      pidx = (int*)     (w + 40 * MB);   // 8MB
    int*      fidx = (int*)     (w + 48 * MB);   // 64KB
    _Float16* xh   = (_Float16*)d_out;           // 32MB scratch; gather overwrites later

    vq_split_hi  <<<dim3((T_TOKENS * DIM) / 1024), 256, 0, stream>>>(x, xh);
    vq_split_hilo<<<dim3((N_CODES  * DIM) / 1024), 256, 0, stream>>>(cb, ch, cl);
    vq_gemm_top2 <<<dim3(NBLK, T_TOKENS / BM), 256, 0, stream>>>(xh, ch, cl, pval, pidx);
    vq_reduce_phase2<<<dim3(T_TOKENS), 128, 0, stream>>>(pval, pidx, x, cb, fidx);
    vq_gather    <<<dim3(T_TOKENS), 256, 0, stream>>>(cb, fidx, out);
  } else {
    vq_naive<<<dim3(T_TOKENS), 256, 0, stream>>>(x, cb, out);
  }
}

// Round 2
// 648.465 us; speedup vs baseline: 1.4580x; 1.4580x over previous
//
#include <hip/hip_runtime.h>
#include <stdint.h>

// CodebookLayer (VQ snap): logits = x @ cb^T, argmax over 8192 codes, gather rows.
// R2: single fp16 GEMM (err std ~0.022, EPS=0.25 => ~11 sigma pairwise margin),
// XOR-swizzled LDS layout (kills the 4-way ds_read_b128 bank conflict seen in R1:
// SQ_LDS_BANK_CONFLICT=5e7), per-chunk top-2 candidates + exact fp64 recheck of
// anything within EPS of the max, reduce fused with the gather.

#define T_TOKENS 16384
#define N_CODES  8192
#define DIM      1024
#define BM 128
#define BN 128
#define BK 32
#define NBLK (N_CODES / BN)   // 64 code chunks
#define KITERS (DIM / BK)     // 32
#define EPS 0.25f
#define MAXCAND 32

typedef _Float16 half8  __attribute__((ext_vector_type(8)));
typedef _Float16 half4v __attribute__((ext_vector_type(4)));
typedef float    f32x4  __attribute__((ext_vector_type(4)));

// async global->LDS, 16B per lane; LDS dest = wave-uniform base + lane*16
#define GLD16(gp, lp) \
  __builtin_amdgcn_global_load_lds((__attribute__((address_space(1))) void*)(gp), \
                                   (__attribute__((address_space(3))) void*)(lp), 16, 0, 0)

// ------------------------------------------------------------------ prep (fused)
// blocks [0, 16384): x (fp32, 16M elems) -> xh (fp16)
// blocks [16384, 24576): cb (fp32, 8M elems) -> ch (fp16)
__global__ __launch_bounds__(256) void vq_prep(const float* __restrict__ x,
                                               const float* __restrict__ cb,
                                               _Float16* __restrict__ xh,
                                               _Float16* __restrict__ ch) {
  size_t b = blockIdx.x;
  const float* src; _Float16* dst;
  if (b < 16384) { src = x;  dst = xh; }
  else           { b -= 16384; src = cb; dst = ch; }
  const size_t i = (b * 256 + threadIdx.x) * 4;
  const float4 v = *(const float4*)(src + i);
  half4v h = {(_Float16)v.x, (_Float16)v.y, (_Float16)v.z, (_Float16)v.w};
  *(half4v*)(dst + i) = h;
}

// ---------------------------------------------------------------- GEMM + top-2
__global__ __launch_bounds__(256) void vq_gemm_top2(
    const _Float16* __restrict__ xh,   // [T][D]
    const _Float16* __restrict__ ch,   // [C][D]
    float* __restrict__ pval,          // [T][NBLK][2]
    int*   __restrict__ pidx)          // [T][NBLK][2]
{
  __shared__ _Float16 As[BM * BK];     // 8KB, swizzled chunk layout
  __shared__ _Float16 Bs[BN * BK];     // 8KB, swizzled chunk layout
  __shared__ float mv1[BM][2]; __shared__ float mv2[BM][2];
  __shared__ int   mi1[BM][2]; __shared__ int   mi2[BM][2];

  const int t    = threadIdx.x;
  const int wave = t >> 6;
  const int lane = t & 63;
  const int l15  = lane & 15;
  const int quad = lane >> 4;
  const int mb   = blockIdx.y * BM;    // token base
  const int nb   = blockIdx.x * BN;    // code base
  const int wm   = (wave >> 1) * 64;   // wave row base within tile
  const int wn   = (wave & 1) * 64;    // wave col base within tile

  // Staging: LDS chunk c (16B) holds global (row = c>>2, kchunk = (c&3) ^ ((row>>1)&3)).
  // XOR swizzle => any 8 consecutive lanes' b128 reads cover all 32 banks.
  const int c0 = t, c1 = t + 256;
  const int r0 = c0 >> 2, kc0 = (((c0 & 3) ^ ((r0 >> 1) & 3))) * 8;
  const int r1 = c1 >> 2, kc1 = (((c1 & 3) ^ ((r1 >> 1) & 3))) * 8;

  const _Float16* ax0 = xh + (size_t)(mb + r0) * DIM + kc0;
  const _Float16* ax1 = xh + (size_t)(mb + r1) * DIM + kc1;
  const _Float16* bx0 = ch + (size_t)(nb + r0) * DIM + kc0;
  const _Float16* bx1 = ch + (size_t)(nb + r1) * DIM + kc1;

  // Fragment read swizzle: chunk = row*4 + (quad ^ ((row>>1)&3)); row>>1 mod 4
  // depends only on l15 (wm, s*16 are multiples of 8 in row>>1).
  const int sw = quad ^ ((l15 >> 1) & 3);

  f32x4 acc[4][4];
#pragma unroll
  for (int i = 0; i < 4; ++i)
#pragma unroll
    for (int j = 0; j < 4; ++j)
      acc[i][j] = (f32x4){0.f, 0.f, 0.f, 0.f};

  for (int kt = 0; kt < KITERS; ++kt) {
    GLD16(ax0, &As[c0 * 8]);
    GLD16(ax1, &As[c1 * 8]);
    GLD16(bx0, &Bs[c0 * 8]);
    GLD16(bx1, &Bs[c1 * 8]);
    ax0 += BK; ax1 += BK; bx0 += BK; bx1 += BK;
    __syncthreads();

    half8 a[4], b[4];
#pragma unroll
    for (int s = 0; s < 4; ++s) {
      const int rowa = wm + s * 16 + l15;
      const int rowb = wn + s * 16 + l15;
      a[s] = *(const half8*)&As[(rowa * 4 + sw) * 8];
      b[s] = *(const half8*)&Bs[(rowb * 4 + sw) * 8];
    }
#pragma unroll
    for (int i = 0; i < 4; ++i)
#pragma unroll
      for (int j = 0; j < 4; ++j)
        acc[i][j] = __builtin_amdgcn_mfma_f32_16x16x32_f16(a[i], b[j], acc[i][j], 0, 0, 0);
    __syncthreads();
  }

  // Epilogue: per-row top-2 over this block's 128 codes.
  // C/D layout: acc[i][j][r] = logits[wm + i*16 + quad*4 + r][wn + j*16 + l15]
#pragma unroll
  for (int i = 0; i < 4; ++i) {
#pragma unroll
    for (int r = 0; r < 4; ++r) {
      float v1 = -1e30f, v2 = -1e30f; int i1 = -1, i2 = -1;
#pragma unroll
      for (int j = 0; j < 4; ++j) {
        const float v = acc[i][j][r];
        const int idx = nb + wn + j * 16 + l15;
        if (v > v1) { v2 = v1; i2 = i1; v1 = v; i1 = idx; }
        else if (v > v2) { v2 = v; i2 = idx; }
      }
#pragma unroll
      for (int m = 1; m <= 8; m <<= 1) {
        const float bv1 = __shfl_xor(v1, m, 64);
        const int   bi1 = __shfl_xor(i1, m, 64);
        const float bv2 = __shfl_xor(v2, m, 64);
        const int   bi2 = __shfl_xor(i2, m, 64);
        if (bv1 > v1) {
          const float nv2 = (bv2 > v1) ? bv2 : v1;
          const int   ni2 = (bv2 > v1) ? bi2 : i1;
          v1 = bv1; i1 = bi1; v2 = nv2; i2 = ni2;
        } else if (bv1 > v2) { v2 = bv1; i2 = bi1; }
      }
      if (l15 == 0) {
        const int row = wm + i * 16 + quad * 4 + r;   // 0..127
        mv1[row][wave & 1] = v1; mi1[row][wave & 1] = i1;
        mv2[row][wave & 1] = v2; mi2[row][wave & 1] = i2;
      }
    }
  }
  __syncthreads();
  if (t < BM) {
    float v1 = mv1[t][0]; int i1 = mi1[t][0];
    float v2 = mv2[t][0]; int i2 = mi2[t][0];
    const float bv1 = mv1[t][1]; const int bi1 = mi1[t][1];
    const float bv2 = mv2[t][1]; const int bi2 = mi2[t][1];
    if (bv1 > v1) {
      const float nv2 = (bv2 > v1) ? bv2 : v1;
      const int   ni2 = (bv2 > v1) ? bi2 : i1;
      v1 = bv1; i1 = bi1; v2 = nv2; i2 = ni2;
    } else if (bv1 > v2) { v2 = bv1; i2 = bi1; }
    const size_t o = ((size_t)(mb + t) * NBLK + blockIdx.x) * 2;
    pval[o] = v1; pval[o + 1] = v2;
    pidx[o] = i1; pidx[o + 1] = i2;
  }
}

// ------------------------------------------- reduce + fp64 recheck + gather
__global__ __launch_bounds__(128) void vq_reduce_gather(
    const float* __restrict__ pval, const int* __restrict__ pidx,
    const float* __restrict__ x, const float* __restrict__ cb,
    float* __restrict__ out)
{
  __shared__ float swmax[2];
  __shared__ int   scand[MAXCAND];
  __shared__ int   scnt;
  __shared__ double sdot[2];
  __shared__ double sbest;
  __shared__ int    sbesti;

  const int tkn  = blockIdx.x;
  const int t    = threadIdx.x;   // 128
  const int lane = t & 63;
  const int wv   = t >> 6;

  const float v = pval[(size_t)tkn * (2 * NBLK) + t];
  const int   ci = pidx[(size_t)tkn * (2 * NBLK) + t];

  // global max over the 128 candidate values
  float m = v;
#pragma unroll
  for (int d = 1; d < 64; d <<= 1) m = fmaxf(m, __shfl_xor(m, d, 64));
  if (t == 0) scnt = 0;
  if (lane == 0) swmax[wv] = m;
  __syncthreads();
  const float M = fmaxf(swmax[0], swmax[1]);

  if (v >= M - EPS) {
    const int p = atomicAdd(&scnt, 1);
    if (p < MAXCAND) scand[p] = ci;
  }
  __syncthreads();
  int cnt = scnt; if (cnt > MAXCAND) cnt = MAXCAND;

  int code;
  if (cnt == 1) {
    code = scand[0];
  } else {
    if (t == 0) { sbest = -1e300; sbesti = N_CODES; }
    __syncthreads();
    const float* xr = x + (size_t)tkn * DIM;
    for (int k = 0; k < cnt; ++k) {
      const int c = scand[k];
      const float* cr = cb + (size_t)c * DIM;
      double s = 0.0;
      for (int d = t; d < DIM; d += 128) s += (double)xr[d] * (double)cr[d];
#pragma unroll
      for (int d = 1; d < 64; d <<= 1) s += __shfl_xor(s, d, 64);
      if (lane == 0) sdot[wv] = s;
      __syncthreads();
      if (t == 0) {
        const double tot = sdot[0] + sdot[1];
        if (tot > sbest || (tot == sbest && c < sbesti)) { sbest = tot; sbesti = c; }
      }
      __syncthreads();
    }
    code = sbesti;
  }

  // gather: out[tkn] = cb[code]
  const float4* src = (const float4*)(cb + (size_t)code * DIM);
  float4*       dst = (float4*)(out + (size_t)tkn * DIM);
  dst[t]       = src[t];
  dst[t + 128] = src[t + 128];
}

// ------------------------------------------------- fallback (ws too small)
__global__ __launch_bounds__(256) void vq_naive(const float* __restrict__ x,
                                                const float* __restrict__ cb,
                                                float* __restrict__ out) {
  __shared__ float xs[DIM];
  __shared__ float bv[256];
  __shared__ int   bix[256];
  const int tkn = blockIdx.x;
  const int t = threadIdx.x;
  for (int d = t; d < DIM; d += 256) xs[d] = x[(size_t)tkn * DIM + d];
  __syncthreads();
  float best = -1e30f; int bi = N_CODES;
  for (int c = t; c < N_CODES; c += 256) {
    const float* cr = cb + (size_t)c * DIM;
    float s = 0.f;
    for (int d = 0; d < DIM; ++d) s += xs[d] * cr[d];
    if (s > best || (s == best && c < bi)) { best = s; bi = c; }
  }
  bv[t] = best; bix[t] = bi;
  __syncthreads();
  for (int off = 128; off > 0; off >>= 1) {
    if (t < off) {
      if (bv[t + off] > bv[t] || (bv[t + off] == bv[t] && bix[t + off] < bix[t])) {
        bv[t] = bv[t + off]; bix[t] = bix[t + off];
      }
    }
    __syncthreads();
  }
  const int code = bix[0];
  for (int d = t; d < DIM; d += 256)
    out[(size_t)tkn * DIM + d] = cb[(size_t)code * DIM + d];
}

// ---------------------------------------------------------------------- launch
extern "C" void kernel_launch(void* const* d_in, const int* in_sizes, int n_in,
                              void* d_out, int out_size, void* d_ws, size_t ws_size,
                              hipStream_t stream) {
  const float* x  = (const float*)d_in[0];   // [16384][1024]
  const float* cb = (const float*)d_in[1];   // [8192][1024]
  float* out = (float*)d_out;

  const size_t MB = 1024 * 1024;
  const size_t need = 32 * MB;
  if (ws_size >= need) {
    char* w = (char*)d_ws;
    _Float16* ch   = (_Float16*)(w);             // 16MB
    float*    pval = (float*)   (w + 16 * MB);   // 8MB
    int*      pidx = (int*)     (w + 24 * MB);   // 8MB
    _Float16* xh   = (_Float16*)d_out;           // 32MB scratch; reduce_gather overwrites

    vq_prep<<<dim3(24576), 256, 0, stream>>>(x, cb, xh, ch);
    vq_gemm_top2<<<dim3(NBLK, T_TOKENS / BM), 256, 0, stream>>>(xh, ch, pval, pidx);
    vq_reduce_gather<<<dim3(T_TOKENS), 128, 0, stream>>>(pval, pidx, x, cb, out);
  } else {
    vq_naive<<<dim3(T_TOKENS), 256, 0, stream>>>(x, cb, out);
  }
}

// Round 3
// 530.349 us; speedup vs baseline: 1.7828x; 1.2227x over previous
//
#include <hip/hip_runtime.h>
#include <stdint.h>

// CodebookLayer (VQ snap): logits = x @ cb^T, argmax over 8192 codes, gather rows.
// R3: fp16 MFMA GEMM with double-buffered LDS (prefetch k+1 before computing k,
// one barrier per kt => staging latency overlaps MFMA; R2 was barrier-drain bound
// at MfmaUtil 22%), XOR-swizzled LDS (R1 bank conflicts 5e7 -> 1.3e5), packed-key
// top-2 epilogue (value+idx in one u32 => half the shuffle count), exact fp64
// recheck of all candidates within EPS of the max, reduce fused with gather.

#define T_TOKENS 16384
#define N_CODES  8192
#define DIM      1024
#define BM 128
#define BN 128
#define BK 32
#define NBLK (N_CODES / BN)   // 64 code chunks
#define KITERS (DIM / BK)     // 32
#define EPS 0.25f
#define MAXCAND 32

typedef _Float16 half8  __attribute__((ext_vector_type(8)));
typedef _Float16 half4v __attribute__((ext_vector_type(4)));
typedef float    f32x4  __attribute__((ext_vector_type(4)));

// async global->LDS, 16B per lane; LDS dest = wave-uniform base + lane*16
#define GLD16(gp, lp) \
  __builtin_amdgcn_global_load_lds((__attribute__((address_space(1))) void*)(gp), \
                                   (__attribute__((address_space(3))) void*)(lp), 16, 0, 0)

// monotone f32 -> u32: order-preserving, larger float => larger uint
__device__ inline uint32_t f32_key(float v) {
  uint32_t b = __float_as_uint(v);
  return (b & 0x80000000u) ? ~b : (b | 0x80000000u);
}
__device__ inline float key_f32(uint32_t u) {
  uint32_t b = (u & 0x80000000u) ? (u & 0x7FFFFFFFu) : ~u;
  return __uint_as_float(b);
}

// ------------------------------------------------------------------ prep (fused)
__global__ __launch_bounds__(256) void vq_prep(const float* __restrict__ x,
                                               const float* __restrict__ cb,
                                               _Float16* __restrict__ xh,
                                               _Float16* __restrict__ ch) {
  size_t b = blockIdx.x;
  const float* src; _Float16* dst;
  if (b < 16384) { src = x;  dst = xh; }
  else           { b -= 16384; src = cb; dst = ch; }
  const size_t i = (b * 256 + threadIdx.x) * 4;
  const float4 v = *(const float4*)(src + i);
  half4v h = {(_Float16)v.x, (_Float16)v.y, (_Float16)v.z, (_Float16)v.w};
  *(half4v*)(dst + i) = h;
}

// ---------------------------------------------------------------- GEMM + top-2
__global__ __launch_bounds__(256) void vq_gemm_top2(
    const _Float16* __restrict__ xh,   // [T][D]
    const _Float16* __restrict__ ch,   // [C][D]
    float* __restrict__ pval,          // [T][NBLK][2]
    int*   __restrict__ pidx)          // [T][NBLK][2]
{
  // double-buffered staging: [stage][ A(8KB) | B(8KB) ] = 32KB total.
  __shared__ _Float16 smem[2][BM * BK + BN * BK];

  const int t    = threadIdx.x;
  const int wave = t >> 6;
  const int lane = t & 63;
  const int l15  = lane & 15;
  const int quad = lane >> 4;
  const int mb   = blockIdx.y * BM;    // token base
  const int nb   = blockIdx.x * BN;    // code base
  const int wm   = (wave >> 1) * 64;   // wave row base within tile
  const int wn   = (wave & 1) * 64;    // wave col base within tile

  // Staging: LDS chunk c (16B) holds global (row = c>>2, kchunk = (c&3) ^ ((row>>1)&3)).
  // XOR swizzle => any 8 consecutive lanes' b128 reads cover all 32 banks.
  const int c0 = t, c1 = t + 256;
  const int r0 = c0 >> 2, kc0 = (((c0 & 3) ^ ((r0 >> 1) & 3))) * 8;
  const int r1 = c1 >> 2, kc1 = (((c1 & 3) ^ ((r1 >> 1) & 3))) * 8;

  const _Float16* ax0 = xh + (size_t)(mb + r0) * DIM + kc0;
  const _Float16* ax1 = xh + (size_t)(mb + r1) * DIM + kc1;
  const _Float16* bx0 = ch + (size_t)(nb + r0) * DIM + kc0;
  const _Float16* bx1 = ch + (size_t)(nb + r1) * DIM + kc1;

  // Fragment read swizzle: chunk = row*4 + (quad ^ ((row>>1)&3)).
  const int sw = quad ^ ((l15 >> 1) & 3);

  f32x4 acc[4][4];
#pragma unroll
  for (int i = 0; i < 4; ++i)
#pragma unroll
    for (int j = 0; j < 4; ++j)
      acc[i][j] = (f32x4){0.f, 0.f, 0.f, 0.f};

  // prologue: stage kt=0 into buffer 0
  {
    _Float16* As = smem[0];
    _Float16* Bs = smem[0] + BM * BK;
    GLD16(ax0, &As[c0 * 8]);
    GLD16(ax1, &As[c1 * 8]);
    GLD16(bx0, &Bs[c0 * 8]);
    GLD16(bx1, &Bs[c1 * 8]);
    ax0 += BK; ax1 += BK; bx0 += BK; bx1 += BK;
  }
  __syncthreads();

  for (int kt = 0; kt < KITERS; ++kt) {
    // prefetch kt+1 into the other buffer; in flight during this kt's compute
    if (kt != KITERS - 1) {
      _Float16* As = smem[(kt + 1) & 1];
      _Float16* Bs = smem[(kt + 1) & 1] + BM * BK;
      GLD16(ax0, &As[c0 * 8]);
      GLD16(ax1, &As[c1 * 8]);
      GLD16(bx0, &Bs[c0 * 8]);
      GLD16(bx1, &Bs[c1 * 8]);
      ax0 += BK; ax1 += BK; bx0 += BK; bx1 += BK;
    }

    const _Float16* As = smem[kt & 1];
    const _Float16* Bs = smem[kt & 1] + BM * BK;
    half8 a[4], b[4];
#pragma unroll
    for (int s = 0; s < 4; ++s) {
      const int rowa = wm + s * 16 + l15;
      const int rowb = wn + s * 16 + l15;
      a[s] = *(const half8*)&As[(rowa * 4 + sw) * 8];
      b[s] = *(const half8*)&Bs[(rowb * 4 + sw) * 8];
    }
#pragma unroll
    for (int i = 0; i < 4; ++i)
#pragma unroll
      for (int j = 0; j < 4; ++j)
        acc[i][j] = __builtin_amdgcn_mfma_f32_16x16x32_f16(a[i], b[j], acc[i][j], 0, 0, 0);
    __syncthreads();   // also drains vmcnt for the prefetch (post-compute)
  }

  // Epilogue: per-row top-2 over this block's 128 codes, packed keys.
  // key = (monotone_u32(value) & ~0x7F) | (127 - idx_in_chunk); idx_in_chunk < 128.
  // Value decode error <= 127 ulp (~0.01 at |v|<=512) -- absorbed by EPS recheck.
  // C/D layout: acc[i][j][r] = logits[wm + i*16 + quad*4 + r][wn + j*16 + l15]
  uint32_t* mk = (uint32_t*)smem;   // overlay: [128 rows][2 wave-halves][2 ranks]

#pragma unroll
  for (int i = 0; i < 4; ++i) {
#pragma unroll
    for (int r = 0; r < 4; ++r) {
      uint32_t k1 = 0, k2 = 0;
#pragma unroll
      for (int j = 0; j < 4; ++j) {
        const uint32_t key = (f32_key(acc[i][j][r]) & 0xFFFFFF80u) |
                             (127u - (uint32_t)(wn + j * 16 + l15));
        if (key > k1) { k2 = k1; k1 = key; }
        else if (key > k2) { k2 = key; }
      }
#pragma unroll
      for (int m = 1; m <= 8; m <<= 1) {
        const uint32_t o1 = __shfl_xor(k1, m, 64);
        const uint32_t o2 = __shfl_xor(k2, m, 64);
        if (o1 > k1) { k2 = (k1 > o2 ? k1 : o2); k1 = o1; }
        else         { k2 = (o1 > k2 ? o1 : k2); }
      }
      if (l15 == 0) {
        const int row = wm + i * 16 + quad * 4 + r;   // 0..127
        mk[(row * 2 + (wave & 1)) * 2 + 0] = k1;
        mk[(row * 2 + (wave & 1)) * 2 + 1] = k2;
      }
    }
  }
  __syncthreads();
  if (t < BM) {
    const uint32_t a1 = mk[t * 4 + 0], a2 = mk[t * 4 + 1];
    const uint32_t b1 = mk[t * 4 + 2], b2 = mk[t * 4 + 3];
    uint32_t k1, k2;
    if (b1 > a1) { k1 = b1; k2 = (a1 > b2 ? a1 : b2); }
    else         { k1 = a1; k2 = (b1 > a2 ? b1 : a2); }
    const size_t o = ((size_t)(mb + t) * NBLK + blockIdx.x) * 2;
    pval[o]     = key_f32(k1);
    pval[o + 1] = key_f32(k2);
    pidx[o]     = nb + 127 - (int)(k1 & 0x7Fu);
    pidx[o + 1] = nb + 127 - (int)(k2 & 0x7Fu);
  }
}

// ------------------------------------------- reduce + fp64 recheck + gather
__global__ __launch_bounds__(128) void vq_reduce_gather(
    const float* __restrict__ pval, const int* __restrict__ pidx,
    const float* __restrict__ x, const float* __restrict__ cb,
    float* __restrict__ out)
{
  __shared__ float swmax[2];
  __shared__ int   scand[MAXCAND];
  __shared__ int   scnt;
  __shared__ double sdot[2];
  __shared__ double sbest;
  __shared__ int    sbesti;

  const int tkn  = blockIdx.x;
  const int t    = threadIdx.x;   // 128
  const int lane = t & 63;
  const int wv   = t >> 6;

  const float v  = pval[(size_t)tkn * (2 * NBLK) + t];
  const int   ci = pidx[(size_t)tkn * (2 * NBLK) + t];

  float m = v;
#pragma unroll
  for (int d = 1; d < 64; d <<= 1) m = fmaxf(m, __shfl_xor(m, d, 64));
  if (t == 0) scnt = 0;
  if (lane == 0) swmax[wv] = m;
  __syncthreads();
  const float M = fmaxf(swmax[0], swmax[1]);

  if (v >= M - EPS) {
    const int p = atomicAdd(&scnt, 1);
    if (p < MAXCAND) scand[p] = ci;
  }
  __syncthreads();
  int cnt = scnt; if (cnt > MAXCAND) cnt = MAXCAND;

  int code;
  if (cnt == 1) {
    code = scand[0];
  } else {
    if (t == 0) { sbest = -1e300; sbesti = N_CODES; }
    __syncthreads();
    const float* xr = x + (size_t)tkn * DIM;
    for (int k = 0; k < cnt; ++k) {
      const int c = scand[k];
      const float* cr = cb + (size_t)c * DIM;
      double s = 0.0;
      for (int d = t; d < DIM; d += 128) s += (double)xr[d] * (double)cr[d];
#pragma unroll
      for (int d = 1; d < 64; d <<= 1) s += __shfl_xor(s, d, 64);
      if (lane == 0) sdot[wv] = s;
      __syncthreads();
      if (t == 0) {
        const double tot = sdot[0] + sdot[1];
        if (tot > sbest || (tot == sbest && c < sbesti)) { sbest = tot; sbesti = c; }
      }
      __syncthreads();
    }
    code = sbesti;
  }

  const float4* src = (const float4*)(cb + (size_t)code * DIM);
  float4*       dst = (float4*)(out + (size_t)tkn * DIM);
  dst[t]       = src[t];
  dst[t + 128] = src[t + 128];
}

// ------------------------------------------------- fallback (ws too small)
__global__ __launch_bounds__(256) void vq_naive(const float* __restrict__ x,
                                                const float* __restrict__ cb,
                                                float* __restrict__ out) {
  __shared__ float xs[DIM];
  __shared__ float bv[256];
  __shared__ int   bix[256];
  const int tkn = blockIdx.x;
  const int t = threadIdx.x;
  for (int d = t; d < DIM; d += 256) xs[d] = x[(size_t)tkn * DIM + d];
  __syncthreads();
  float best = -1e30f; int bi = N_CODES;
  for (int c = t; c < N_CODES; c += 256) {
    const float* cr = cb + (size_t)c * DIM;
    float s = 0.f;
    for (int d = 0; d < DIM; ++d) s += xs[d] * cr[d];
    if (s > best || (s == best && c < bi)) { best = s; bi = c; }
  }
  bv[t] = best; bix[t] = bi;
  __syncthreads();
  for (int off = 128; off > 0; off >>= 1) {
    if (t < off) {
      if (bv[t + off] > bv[t] || (bv[t + off] == bv[t] && bix[t + off] < bix[t])) {
        bv[t] = bv[t + off]; bix[t] = bix[t + off];
      }
    }
    __syncthreads();
  }
  const int code = bix[0];
  for (int d = t; d < DIM; d += 256)
    out[(size_t)tkn * DIM + d] = cb[(size_t)code * DIM + d];
}

// ---------------------------------------------------------------------- launch
extern "C" void kernel_launch(void* const* d_in, const int* in_sizes, int n_in,
                              void* d_out, int out_size, void* d_ws, size_t ws_size,
                              hipStream_t stream) {
  const float* x  = (const float*)d_in[0];   // [16384][1024]
  const float* cb = (const float*)d_in[1];   // [8192][1024]
  float* out = (float*)d_out;

  const size_t MB = 1024 * 1024;
  const size_t need = 32 * MB;
  if (ws_size >= need) {
    char* w = (char*)d_ws;
    _Float16* ch   = (_Float16*)(w);             // 16MB
    float*    pval = (float*)   (w + 16 * MB);   // 8MB
    int*      pidx = (int*)     (w + 24 * MB);   // 8MB
    _Float16* xh   = (_Float16*)d_out;           // 32MB scratch; reduce_gather overwrites

    vq_prep<<<dim3(24576), 256, 0, stream>>>(x, cb, xh, ch);
    vq_gemm_top2<<<dim3(NBLK, T_TOKENS / BM), 256, 0, stream>>>(xh, ch, pval, pidx);
    vq_reduce_gather<<<dim3(T_TOKENS), 128, 0, stream>>>(pval, pidx, x, cb, out);
  } else {
    vq_naive<<<dim3(T_TOKENS), 256, 0, stream>>>(x, cb, out);
  }
}

// Round 4
// 366.057 us; speedup vs baseline: 2.5829x; 1.4488x over previous
//
#include <hip/hip_runtime.h>
#include <stdint.h>

// CodebookLayer (VQ snap): logits = x @ cb^T, argmax over 8192 codes, gather rows.
// R4: MX-fp8 GEMM (mfma_scale_f32_32x32x64_f8f6f4, scales=1.0) -- halves both the
// LDS traffic and the MFMA time vs R3's fp16 (which sat at the m97-structure
// plateau, 712 TF). M/N swapped (M=codes, N=tokens) so each lane owns in-register
// code-slices of one token => cheap med3-based in-lane top-3 epilogue (no
// butterfly storm). fp8 logit err std ~1.6 => EPS=13 (5.6 sigma pairwise) +
// top-3 per 128-code chunk keeps the exact-fp64-recheck candidate set a superset
// of the true argmax with overwhelming probability. Recheck resolves order.

#define T_TOKENS 16384
#define N_CODES  8192
#define DIM      1024
#define BM 128                  // codes per block (M = codes)
#define BN 128                  // tokens per block
#define BK 64                   // K bytes staged per iter (fp8)
#define NBLK (N_CODES / BM)     // 64 code chunks
#define KITERS (DIM / BK)       // 16
#define EPS 13.0f
#define MAXCAND 48

typedef int   int8v  __attribute__((ext_vector_type(8)));
typedef int   int4v  __attribute__((ext_vector_type(4)));
typedef float f32x16 __attribute__((ext_vector_type(16)));

// async global->LDS, 16B per lane; LDS dest = wave-uniform base + lane*16
#define GLD16(gp, lp) \
  __builtin_amdgcn_global_load_lds((__attribute__((address_space(1))) void*)(gp), \
                                   (__attribute__((address_space(3))) void*)(lp), 16, 0, 0)

__device__ inline uint32_t umax(uint32_t a, uint32_t b) { return a > b ? a : b; }
__device__ inline uint32_t umin(uint32_t a, uint32_t b) { return a < b ? a : b; }
// compiler pattern-matches to v_med3_u32
__device__ inline uint32_t umed3(uint32_t a, uint32_t b, uint32_t c) {
  return umax(umin(a, b), umin(umax(a, b), c));
}

// monotone f32 -> u32 (larger float => larger uint)
__device__ inline uint32_t f32_key(float v) {
  int32_t b = (int32_t)__float_as_uint(v);
  return (uint32_t)(b ^ ((b >> 31) | (int32_t)0x80000000));
}
__device__ inline float key_f32(uint32_t u) {
  uint32_t b = (u & 0x80000000u) ? (u & 0x7FFFFFFFu) : ~u;
  return __uint_as_float(b);
}

// ------------------------------------------------------------------ prep (fused)
// blocks [0,16384): x (fp32) -> xq (fp8 e4m3); [16384,24576): cb -> cq
__global__ __launch_bounds__(256) void vq_prep(const float* __restrict__ x,
                                               const float* __restrict__ cbm,
                                               uint8_t* __restrict__ xq,
                                               uint8_t* __restrict__ cq) {
  size_t b = blockIdx.x;
  const float* src; uint8_t* dst;
  if (b < 16384) { src = x;  dst = xq; }
  else           { b -= 16384; src = cbm; dst = cq; }
  const size_t i = b * 256 + threadIdx.x;
  const float4 v = ((const float4*)src)[i];
  uint32_t r = __builtin_amdgcn_cvt_pk_fp8_f32(v.x, v.y, 0, false);
  r = __builtin_amdgcn_cvt_pk_fp8_f32(v.z, v.w, (int)r, true);
  ((uint32_t*)dst)[i] = r;
}

// ---------------------------------------------------------------- GEMM + top-3
// C[code][token]; block = 128 codes x 128 tokens; wave = 64x64 via 2x2 MFMA tiles.
__global__ __launch_bounds__(256) void vq_gemm_top3(
    const uint8_t* __restrict__ cq,   // [C][D] fp8 (A operand)
    const uint8_t* __restrict__ xq,   // [T][D] fp8 (B operand)
    uint32_t* __restrict__ pk)        // [T][NBLK][3] packed keys
{
  // double-buffered staging: per buffer A(8KB) | B(8KB); total 32KB
  __shared__ uint8_t smem[2][2 * BM * BK];

  const int t    = threadIdx.x;
  const int wave = t >> 6;
  const int lane = t & 63;
  const int col  = lane & 31;
  const int hi   = lane >> 5;
  const int cb0  = blockIdx.y * BM;   // code base
  const int tb0  = blockIdx.x * BN;   // token base
  const int wm   = (wave >> 1) * 64;  // code half within block
  const int wn   = (wave & 1) * 64;   // token half within block

  // Staging: slot c in [0,512) per matrix: row = c>>2, stored 16B k-chunk = (c&3)^(row&3).
  // XOR swizzle => fragment reads are 2-way bank aliased (free, m136).
  const int c0 = t, c1 = t + 256;
  const int r0 = c0 >> 2, k0 = ((c0 & 3) ^ (r0 & 3)) * 16;
  const int r1 = c1 >> 2, k1 = ((c1 & 3) ^ (r1 & 3)) * 16;

  const uint8_t* pa0 = cq + (size_t)(cb0 + r0) * DIM + k0;
  const uint8_t* pa1 = cq + (size_t)(cb0 + r1) * DIM + k1;
  const uint8_t* pb0 = xq + (size_t)(tb0 + r0) * DIM + k0;
  const uint8_t* pb1 = xq + (size_t)(tb0 + r1) * DIM + k1;

  f32x16 acc[2][2];
#pragma unroll
  for (int i = 0; i < 2; ++i)
#pragma unroll
    for (int j = 0; j < 2; ++j)
#pragma unroll
      for (int r = 0; r < 16; ++r) acc[i][j][r] = 0.f;

  // prologue: stage kt=0 into buffer 0
  {
    uint8_t* As = smem[0];
    uint8_t* Bs = smem[0] + BM * BK;
    GLD16(pa0, As + c0 * 16); GLD16(pa1, As + c1 * 16);
    GLD16(pb0, Bs + c0 * 16); GLD16(pb1, Bs + c1 * 16);
    pa0 += BK; pa1 += BK; pb0 += BK; pb1 += BK;
  }
  __syncthreads();

  for (int kt = 0; kt < KITERS; ++kt) {
    if (kt != KITERS - 1) {   // prefetch kt+1 into other buffer
      uint8_t* As = smem[(kt + 1) & 1];
      uint8_t* Bs = smem[(kt + 1) & 1] + BM * BK;
      GLD16(pa0, As + c0 * 16); GLD16(pa1, As + c1 * 16);
      GLD16(pb0, Bs + c0 * 16); GLD16(pb1, Bs + c1 * 16);
      pa0 += BK; pa1 += BK; pb0 += BK; pb1 += BK;
    }

    const uint8_t* As = smem[kt & 1];
    const uint8_t* Bs = smem[kt & 1] + BM * BK;
    // A/B fragment: row = lane&31, k-bytes (lane>>5)*32 .. +31 (two 16B chunks)
    int8v a[2], b[2];
    const int j0 = hi * 2;
#pragma unroll
    for (int i = 0; i < 2; ++i) {
      const int ra = wm + i * 32 + col;
      const int4v alo = *(const int4v*)(As + (ra * 4 + (j0 ^ (ra & 3))) * 16);
      const int4v ahi = *(const int4v*)(As + (ra * 4 + ((j0 + 1) ^ (ra & 3))) * 16);
      a[i] = (int8v){alo[0], alo[1], alo[2], alo[3], ahi[0], ahi[1], ahi[2], ahi[3]};
      const int rb = wn + i * 32 + col;
      const int4v blo = *(const int4v*)(Bs + (rb * 4 + (j0 ^ (rb & 3))) * 16);
      const int4v bhi = *(const int4v*)(Bs + (rb * 4 + ((j0 + 1) ^ (rb & 3))) * 16);
      b[i] = (int8v){blo[0], blo[1], blo[2], blo[3], bhi[0], bhi[1], bhi[2], bhi[3]};
    }
#pragma unroll
    for (int i = 0; i < 2; ++i)
#pragma unroll
      for (int j = 0; j < 2; ++j)
        acc[i][j] = __builtin_amdgcn_mfma_scale_f32_32x32x64_f8f6f4(
            a[i], b[j], acc[i][j], 0, 0, 0, 0x7F7F7F7F, 0, 0x7F7F7F7F);
    __syncthreads();
  }

  // Epilogue: per-token top-3 over this block's 128 codes.
  // C/D 32x32 layout: col(token)=lane&31, row(code)=(reg&3)+8*(reg>>2)+4*(lane>>5).
  // key = (monotone(value) & ~0x7F) | (127 - code_in_block); in-lane med3 insert.
  uint32_t* cand = (uint32_t*)smem;   // [128 tokens][2 code-halves][3]
  const int invb = 127 - wm - 4 * hi;
#pragma unroll
  for (int j = 0; j < 2; ++j) {
    uint32_t K1 = 0, K2 = 0, K3 = 0;
#pragma unroll
    for (int i = 0; i < 2; ++i) {
#pragma unroll
      for (int rg = 0; rg < 16; ++rg) {
        const int rowoff = (rg & 3) + 8 * (rg >> 2);
        const uint32_t key = (f32_key(acc[i][j][rg]) & 0xFFFFFF80u)
                           | (uint32_t)(invb - i * 32 - rowoff);
        const uint32_t t3 = umed3(key, K2, K3);
        const uint32_t t2 = umed3(key, K1, K2);
        K1 = umax(key, K1); K2 = t2; K3 = t3;
      }
    }
    // merge row-halves (lane ^ 32 holds same token, other 4-row offset)
    const uint32_t o1 = __shfl_xor(K1, 32, 64);
    const uint32_t o2 = __shfl_xor(K2, 32, 64);
    const uint32_t o3 = __shfl_xor(K3, 32, 64);
    const uint32_t m1 = umin(K1, o1), M2 = umax(K2, o2);
    const uint32_t m2 = umin(K2, o2), M3 = umax(K3, o3);
    K1 = umax(K1, o1);
    const uint32_t nk2 = umax(m1, M2);
    K3 = umax(umax(m2, umin(m1, M2)), M3);
    K2 = nk2;
    if (hi == 0) {
      uint32_t* c = &cand[((wn + j * 32 + col) * 2 + (wave >> 1)) * 3];
      c[0] = K1; c[1] = K2; c[2] = K3;
    }
  }
  __syncthreads();
  if (t < BN) {
    const uint32_t a1 = cand[(t * 2 + 0) * 3 + 0], a2 = cand[(t * 2 + 0) * 3 + 1],
                   a3 = cand[(t * 2 + 0) * 3 + 2];
    const uint32_t b1 = cand[(t * 2 + 1) * 3 + 0], b2 = cand[(t * 2 + 1) * 3 + 1],
                   b3 = cand[(t * 2 + 1) * 3 + 2];
    const uint32_t m1 = umin(a1, b1), M2 = umax(a2, b2);
    const uint32_t m2 = umin(a2, b2), M3 = umax(a3, b3);
    uint32_t* dst = pk + ((size_t)(tb0 + t) * NBLK + blockIdx.y) * 3;
    dst[0] = umax(a1, b1);
    dst[1] = umax(m1, M2);
    dst[2] = umax(umax(m2, umin(m1, M2)), M3);
  }
}

// ------------------------------------------- reduce + fp64 recheck + gather
__global__ __launch_bounds__(256) void vq_reduce_gather(
    const uint32_t* __restrict__ pk, const float* __restrict__ x,
    const float* __restrict__ cb, float* __restrict__ out)
{
  __shared__ float xs[DIM];
  __shared__ uint32_t wmax[4];
  __shared__ int scand[MAXCAND];
  __shared__ int scnt;
  __shared__ double sdot[4];
  __shared__ double sbest;
  __shared__ int sbesti;

  const int tkn = blockIdx.x, t = threadIdx.x, lane = t & 63, wv = t >> 6;
  ((float4*)xs)[t] = ((const float4*)(x + (size_t)tkn * DIM))[t];
  const uint32_t key = (t < 3 * NBLK) ? pk[(size_t)tkn * (3 * NBLK) + t] : 0u;
  uint32_t m = key;
#pragma unroll
  for (int d = 1; d < 64; d <<= 1) m = umax(m, __shfl_xor(m, d, 64));
  if (t == 0) { scnt = 0; sbest = -1e300; sbesti = N_CODES; }
  if (lane == 0) wmax[wv] = m;
  __syncthreads();
  const float Mv = key_f32(umax(umax(wmax[0], wmax[1]), umax(wmax[2], wmax[3])));
  if (t < 3 * NBLK && key_f32(key) >= Mv - EPS) {
    const int p = atomicAdd(&scnt, 1);
    if (p < MAXCAND) scand[p] = (t / 3) * BM + 127 - (int)(key & 127u);
  }
  __syncthreads();
  int cnt = scnt; if (cnt > MAXCAND) cnt = MAXCAND;

  if (cnt > 1) {
    const float4 xv = ((const float4*)xs)[t];
    for (int k = 0; k < cnt; ++k) {
      const int c = scand[k];
      const float4 cv = ((const float4*)(cb + (size_t)c * DIM))[t];
      double s = (double)xv.x * cv.x + (double)xv.y * cv.y
               + (double)xv.z * cv.z + (double)xv.w * cv.w;
#pragma unroll
      for (int d = 1; d < 64; d <<= 1) s += __shfl_xor(s, d, 64);
      if (lane == 0) sdot[wv] = s;
      __syncthreads();
      if (t == 0) {
        const double tot = sdot[0] + sdot[1] + sdot[2] + sdot[3];
        if (tot > sbest || (tot == sbest && c < sbesti)) { sbest = tot; sbesti = c; }
      }
      __syncthreads();
    }
  } else {
    if (t == 0) sbesti = scand[0];
    __syncthreads();
  }
  const int code = sbesti;
  ((float4*)(out + (size_t)tkn * DIM))[t] = ((const float4*)(cb + (size_t)code * DIM))[t];
}

// ------------------------------------------------- fallback (ws too small)
__global__ __launch_bounds__(256) void vq_naive(const float* __restrict__ x,
                                                const float* __restrict__ cb,
                                                float* __restrict__ out) {
  __shared__ float xs[DIM];
  __shared__ float bv[256];
  __shared__ int   bix[256];
  const int tkn = blockIdx.x;
  const int t = threadIdx.x;
  for (int d = t; d < DIM; d += 256) xs[d] = x[(size_t)tkn * DIM + d];
  __syncthreads();
  float best = -1e30f; int bi = N_CODES;
  for (int c = t; c < N_CODES; c += 256) {
    const float* cr = cb + (size_t)c * DIM;
    float s = 0.f;
    for (int d = 0; d < DIM; ++d) s += xs[d] * cr[d];
    if (s > best || (s == best && c < bi)) { best = s; bi = c; }
  }
  bv[t] = best; bix[t] = bi;
  __syncthreads();
  for (int off = 128; off > 0; off >>= 1) {
    if (t < off) {
      if (bv[t + off] > bv[t] || (bv[t + off] == bv[t] && bix[t + off] < bix[t])) {
        bv[t] = bv[t + off]; bix[t] = bix[t + off];
      }
    }
    __syncthreads();
  }
  const int code = bix[0];
  for (int d = t; d < DIM; d += 256)
    out[(size_t)tkn * DIM + d] = cb[(size_t)code * DIM + d];
}

// ---------------------------------------------------------------------- launch
extern "C" void kernel_launch(void* const* d_in, const int* in_sizes, int n_in,
                              void* d_out, int out_size, void* d_ws, size_t ws_size,
                              hipStream_t stream) {
  const float* x  = (const float*)d_in[0];   // [16384][1024]
  const float* cb = (const float*)d_in[1];   // [8192][1024]
  float* out = (float*)d_out;

  const size_t MB = 1024 * 1024;
  const size_t need = 24 * MB + (size_t)T_TOKENS * NBLK * 3 * 4;  // ~36.6MB
  if (ws_size >= need) {
    uint8_t*  xq = (uint8_t*)d_ws;             // 16MB fp8 tokens
    uint8_t*  cq = xq + 16 * MB;               // 8MB  fp8 codebook
    uint32_t* pk = (uint32_t*)(cq + 8 * MB);   // 12.6MB packed keys

    vq_prep<<<dim3(24576), 256, 0, stream>>>(x, cb, xq, cq);
    vq_gemm_top3<<<dim3(T_TOKENS / BN, N_CODES / BM), 256, 0, stream>>>(cq, xq, pk);
    vq_reduce_gather<<<dim3(T_TOKENS), 256, 0, stream>>>(pk, x, cb, out);
  } else {
    vq_naive<<<dim3(T_TOKENS), 256, 0, stream>>>(x, cb, out);
  }
}

// Round 5
// 355.285 us; speedup vs baseline: 2.6612x; 1.0303x over previous
//
#include <hip/hip_runtime.h>
#include <stdint.h>

// CodebookLayer (VQ snap): logits = x @ cb^T, argmax over 8192 codes, gather rows.
// R5: fix the LDS XOR swizzle -- R4 used perm=(row&3) which left slot-mod-8 in
// only 4 bank-groups (SQ_LDS_BANK_CONFLICT back at 5e7, ~4-way). Correct perm is
// (row>>1)&3 (as in R3): slot%8 = (row&1)*4 + (j^((row>>1)&3)) covers all 8
// groups for any 8 consecutive lanes. Also wave-parallel fp64 recheck in
// reduce_gather (one candidate per wave, no per-candidate barriers).

#define T_TOKENS 16384
#define N_CODES  8192
#define DIM      1024
#define BM 128                  // codes per block (M = codes)
#define BN 128                  // tokens per block
#define BK 64                   // K bytes staged per iter (fp8)
#define NBLK (N_CODES / BM)     // 64 code chunks
#define KITERS (DIM / BK)       // 16
#define EPS 13.0f
#define MAXCAND 48

typedef int   int8v  __attribute__((ext_vector_type(8)));
typedef int   int4v  __attribute__((ext_vector_type(4)));
typedef float f32x16 __attribute__((ext_vector_type(16)));

// async global->LDS, 16B per lane; LDS dest = wave-uniform base + lane*16
#define GLD16(gp, lp) \
  __builtin_amdgcn_global_load_lds((__attribute__((address_space(1))) void*)(gp), \
                                   (__attribute__((address_space(3))) void*)(lp), 16, 0, 0)

__device__ inline uint32_t umax(uint32_t a, uint32_t b) { return a > b ? a : b; }
__device__ inline uint32_t umin(uint32_t a, uint32_t b) { return a < b ? a : b; }
// compiler pattern-matches to v_med3_u32
__device__ inline uint32_t umed3(uint32_t a, uint32_t b, uint32_t c) {
  return umax(umin(a, b), umin(umax(a, b), c));
}

// monotone f32 -> u32 (larger float => larger uint)
__device__ inline uint32_t f32_key(float v) {
  int32_t b = (int32_t)__float_as_uint(v);
  return (uint32_t)(b ^ ((b >> 31) | (int32_t)0x80000000));
}
__device__ inline float key_f32(uint32_t u) {
  uint32_t b = (u & 0x80000000u) ? (u & 0x7FFFFFFFu) : ~u;
  return __uint_as_float(b);
}

// ------------------------------------------------------------------ prep (fused)
// blocks [0,16384): x (fp32) -> xq (fp8 e4m3); [16384,24576): cb -> cq
__global__ __launch_bounds__(256) void vq_prep(const float* __restrict__ x,
                                               const float* __restrict__ cbm,
                                               uint8_t* __restrict__ xq,
                                               uint8_t* __restrict__ cq) {
  size_t b = blockIdx.x;
  const float* src; uint8_t* dst;
  if (b < 16384) { src = x;  dst = xq; }
  else           { b -= 16384; src = cbm; dst = cq; }
  const size_t i = b * 256 + threadIdx.x;
  const float4 v = ((const float4*)src)[i];
  uint32_t r = __builtin_amdgcn_cvt_pk_fp8_f32(v.x, v.y, 0, false);
  r = __builtin_amdgcn_cvt_pk_fp8_f32(v.z, v.w, (int)r, true);
  ((uint32_t*)dst)[i] = r;
}

// ---------------------------------------------------------------- GEMM + top-3
// C[code][token]; block = 128 codes x 128 tokens; wave = 64x64 via 2x2 MFMA tiles.
__global__ __launch_bounds__(256) void vq_gemm_top3(
    const uint8_t* __restrict__ cq,   // [C][D] fp8 (A operand)
    const uint8_t* __restrict__ xq,   // [T][D] fp8 (B operand)
    uint32_t* __restrict__ pk)        // [T][NBLK][3] packed keys
{
  // double-buffered staging: per buffer A(8KB) | B(8KB); total 32KB
  __shared__ uint8_t smem[2][2 * BM * BK];

  const int t    = threadIdx.x;
  const int wave = t >> 6;
  const int lane = t & 63;
  const int col  = lane & 31;
  const int hi   = lane >> 5;
  const int cb0  = blockIdx.y * BM;   // code base
  const int tb0  = blockIdx.x * BN;   // token base
  const int wm   = (wave >> 1) * 64;  // code half within block
  const int wn   = (wave & 1) * 64;   // token half within block

  // Staging: slot c in [0,512): row = c>>2, stored 16B k-chunk = (c&3)^((row>>1)&3).
  // slot%8 = (row&1)*4 + (j ^ ((row>>1)&3)) -> all 8 bank groups per 8 lanes.
  const int c0 = t, c1 = t + 256;
  const int r0 = c0 >> 2, k0 = ((c0 & 3) ^ ((r0 >> 1) & 3)) * 16;
  const int r1 = c1 >> 2, k1 = ((c1 & 3) ^ ((r1 >> 1) & 3)) * 16;

  const uint8_t* pa0 = cq + (size_t)(cb0 + r0) * DIM + k0;
  const uint8_t* pa1 = cq + (size_t)(cb0 + r1) * DIM + k1;
  const uint8_t* pb0 = xq + (size_t)(tb0 + r0) * DIM + k0;
  const uint8_t* pb1 = xq + (size_t)(tb0 + r1) * DIM + k1;

  f32x16 acc[2][2];
#pragma unroll
  for (int i = 0; i < 2; ++i)
#pragma unroll
    for (int j = 0; j < 2; ++j)
#pragma unroll
      for (int r = 0; r < 16; ++r) acc[i][j][r] = 0.f;

  // prologue: stage kt=0 into buffer 0
  {
    uint8_t* As = smem[0];
    uint8_t* Bs = smem[0] + BM * BK;
    GLD16(pa0, As + c0 * 16); GLD16(pa1, As + c1 * 16);
    GLD16(pb0, Bs + c0 * 16); GLD16(pb1, Bs + c1 * 16);
    pa0 += BK; pa1 += BK; pb0 += BK; pb1 += BK;
  }
  __syncthreads();

  for (int kt = 0; kt < KITERS; ++kt) {
    if (kt != KITERS - 1) {   // prefetch kt+1 into other buffer
      uint8_t* As = smem[(kt + 1) & 1];
      uint8_t* Bs = smem[(kt + 1) & 1] + BM * BK;
      GLD16(pa0, As + c0 * 16); GLD16(pa1, As + c1 * 16);
      GLD16(pb0, Bs + c0 * 16); GLD16(pb1, Bs + c1 * 16);
      pa0 += BK; pa1 += BK; pb0 += BK; pb1 += BK;
    }

    const uint8_t* As = smem[kt & 1];
    const uint8_t* Bs = smem[kt & 1] + BM * BK;
    // A/B fragment: row = lane&31, k-bytes (lane>>5)*32 .. +31 (two 16B chunks)
    int8v a[2], b[2];
    const int j0 = hi * 2;
#pragma unroll
    for (int i = 0; i < 2; ++i) {
      const int ra = wm + i * 32 + col;
      const int pa = (ra >> 1) & 3;
      const int4v alo = *(const int4v*)(As + (ra * 4 + (j0 ^ pa)) * 16);
      const int4v ahi = *(const int4v*)(As + (ra * 4 + ((j0 + 1) ^ pa)) * 16);
      a[i] = (int8v){alo[0], alo[1], alo[2], alo[3], ahi[0], ahi[1], ahi[2], ahi[3]};
      const int rb = wn + i * 32 + col;
      const int pb = (rb >> 1) & 3;
      const int4v blo = *(const int4v*)(Bs + (rb * 4 + (j0 ^ pb)) * 16);
      const int4v bhi = *(const int4v*)(Bs + (rb * 4 + ((j0 + 1) ^ pb)) * 16);
      b[i] = (int8v){blo[0], blo[1], blo[2], blo[3], bhi[0], bhi[1], bhi[2], bhi[3]};
    }
#pragma unroll
    for (int i = 0; i < 2; ++i)
#pragma unroll
      for (int j = 0; j < 2; ++j)
        acc[i][j] = __builtin_amdgcn_mfma_scale_f32_32x32x64_f8f6f4(
            a[i], b[j], acc[i][j], 0, 0, 0, 0x7F7F7F7F, 0, 0x7F7F7F7F);
    __syncthreads();
  }

  // Epilogue: per-token top-3 over this block's 128 codes.
  // C/D 32x32 layout: col(token)=lane&31, row(code)=(reg&3)+8*(reg>>2)+4*(lane>>5).
  // key = (monotone(value) & ~0x7F) | (127 - code_in_block); in-lane med3 insert.
  uint32_t* cand = (uint32_t*)smem;   // [128 tokens][2 code-halves][3]
  const int invb = 127 - wm - 4 * hi;
#pragma unroll
  for (int j = 0; j < 2; ++j) {
    uint32_t K1 = 0, K2 = 0, K3 = 0;
#pragma unroll
    for (int i = 0; i < 2; ++i) {
#pragma unroll
      for (int rg = 0; rg < 16; ++rg) {
        const int rowoff = (rg & 3) + 8 * (rg >> 2);
        const uint32_t key = (f32_key(acc[i][j][rg]) & 0xFFFFFF80u)
                           | (uint32_t)(invb - i * 32 - rowoff);
        const uint32_t t3 = umed3(key, K2, K3);
        const uint32_t t2 = umed3(key, K1, K2);
        K1 = umax(key, K1); K2 = t2; K3 = t3;
      }
    }
    // merge row-halves (lane ^ 32 holds same token, other 4-row offset)
    const uint32_t o1 = __shfl_xor(K1, 32, 64);
    const uint32_t o2 = __shfl_xor(K2, 32, 64);
    const uint32_t o3 = __shfl_xor(K3, 32, 64);
    const uint32_t m1 = umin(K1, o1), M2 = umax(K2, o2);
    const uint32_t m2 = umin(K2, o2), M3 = umax(K3, o3);
    K1 = umax(K1, o1);
    const uint32_t nk2 = umax(m1, M2);
    K3 = umax(umax(m2, umin(m1, M2)), M3);
    K2 = nk2;
    if (hi == 0) {
      uint32_t* c = &cand[((wn + j * 32 + col) * 2 + (wave >> 1)) * 3];
      c[0] = K1; c[1] = K2; c[2] = K3;
    }
  }
  __syncthreads();
  if (t < BN) {
    const uint32_t a1 = cand[(t * 2 + 0) * 3 + 0], a2 = cand[(t * 2 + 0) * 3 + 1],
                   a3 = cand[(t * 2 + 0) * 3 + 2];
    const uint32_t b1 = cand[(t * 2 + 1) * 3 + 0], b2 = cand[(t * 2 + 1) * 3 + 1],
                   b3 = cand[(t * 2 + 1) * 3 + 2];
    const uint32_t m1 = umin(a1, b1), M2 = umax(a2, b2);
    const uint32_t m2 = umin(a2, b2), M3 = umax(a3, b3);
    uint32_t* dst = pk + ((size_t)(tb0 + t) * NBLK + blockIdx.y) * 3;
    dst[0] = umax(a1, b1);
    dst[1] = umax(m1, M2);
    dst[2] = umax(umax(m2, umin(m1, M2)), M3);
  }
}

// ------------------------------------------- reduce + fp64 recheck + gather
__global__ __launch_bounds__(256) void vq_reduce_gather(
    const uint32_t* __restrict__ pk, const float* __restrict__ x,
    const float* __restrict__ cb, float* __restrict__ out)
{
  __shared__ float xs[DIM];
  __shared__ uint32_t wmax[4];
  __shared__ int scand[MAXCAND];
  __shared__ int scnt;
  __shared__ double sdot[MAXCAND];
  __shared__ int sbesti;

  const int tkn = blockIdx.x, t = threadIdx.x, lane = t & 63, wv = t >> 6;
  ((float4*)xs)[t] = ((const float4*)(x + (size_t)tkn * DIM))[t];
  const uint32_t key = (t < 3 * NBLK) ? pk[(size_t)tkn * (3 * NBLK) + t] : 0u;
  uint32_t m = key;
#pragma unroll
  for (int d = 1; d < 64; d <<= 1) m = umax(m, __shfl_xor(m, d, 64));
  if (t == 0) scnt = 0;
  if (lane == 0) wmax[wv] = m;
  __syncthreads();
  const float Mv = key_f32(umax(umax(wmax[0], wmax[1]), umax(wmax[2], wmax[3])));
  if (t < 3 * NBLK && key_f32(key) >= Mv - EPS) {
    const int p = atomicAdd(&scnt, 1);
    if (p < MAXCAND) scand[p] = (t / 3) * BM + 127 - (int)(key & 127u);
  }
  __syncthreads();
  const int cnt = scnt < MAXCAND ? scnt : MAXCAND;

  if (cnt > 1) {
    // wave-parallel: wave wv handles candidates wv, wv+4, ...
    for (int k = wv; k < cnt; k += 4) {
      const int c = scand[k];
      const float* cr = cb + (size_t)c * DIM;
      double s = 0.0;
#pragma unroll
      for (int q = 0; q < 4; ++q) {
        const float4 xv = ((const float4*)xs)[lane + 64 * q];
        const float4 cv = ((const float4*)cr)[lane + 64 * q];
        s += (double)xv.x * cv.x + (double)xv.y * cv.y
           + (double)xv.z * cv.z + (double)xv.w * cv.w;
      }
#pragma unroll
      for (int d = 1; d < 64; d <<= 1) s += __shfl_xor(s, d, 64);
      if (lane == 0) sdot[k] = s;
    }
    __syncthreads();
    if (t == 0) {
      double best = -1e300; int bi = N_CODES;
      for (int k = 0; k < cnt; ++k) {
        const int c = scand[k];
        if (sdot[k] > best || (sdot[k] == best && c < bi)) { best = sdot[k]; bi = c; }
      }
      sbesti = bi;
    }
  } else {
    if (t == 0) sbesti = scand[0];
  }
  __syncthreads();
  const int code = sbesti;
  ((float4*)(out + (size_t)tkn * DIM))[t] = ((const float4*)(cb + (size_t)code * DIM))[t];
}

// ------------------------------------------------- fallback (ws too small)
__global__ __launch_bounds__(256) void vq_naive(const float* __restrict__ x,
                                                const float* __restrict__ cb,
                                                float* __restrict__ out) {
  __shared__ float xs[DIM];
  __shared__ float bv[256];
  __shared__ int   bix[256];
  const int tkn = blockIdx.x;
  const int t = threadIdx.x;
  for (int d = t; d < DIM; d += 256) xs[d] = x[(size_t)tkn * DIM + d];
  __syncthreads();
  float best = -1e30f; int bi = N_CODES;
  for (int c = t; c < N_CODES; c += 256) {
    const float* cr = cb + (size_t)c * DIM;
    float s = 0.f;
    for (int d = 0; d < DIM; ++d) s += xs[d] * cr[d];
    if (s > best || (s == best && c < bi)) { best = s; bi = c; }
  }
  bv[t] = best; bix[t] = bi;
  __syncthreads();
  for (int off = 128; off > 0; off >>= 1) {
    if (t < off) {
      if (bv[t + off] > bv[t] || (bv[t + off] == bv[t] && bix[t + off] < bix[t])) {
        bv[t] = bv[t + off]; bix[t] = bix[t + off];
      }
    }
    __syncthreads();
  }
  const int code = bix[0];
  for (int d = t; d < DIM; d += 256)
    out[(size_t)tkn * DIM + d] = cb[(size_t)code * DIM + d];
}

// ---------------------------------------------------------------------- launch
extern "C" void kernel_launch(void* const* d_in, const int* in_sizes, int n_in,
                              void* d_out, int out_size, void* d_ws, size_t ws_size,
                              hipStream_t stream) {
  const float* x  = (const float*)d_in[0];   // [16384][1024]
  const float* cb = (const float*)d_in[1];   // [8192][1024]
  float* out = (float*)d_out;

  const size_t MB = 1024 * 1024;
  const size_t need = 24 * MB + (size_t)T_TOKENS * NBLK * 3 * 4;  // ~36.6MB
  if (ws_size >= need) {
    uint8_t*  xq = (uint8_t*)d_ws;             // 16MB fp8 tokens
    uint8_t*  cq = xq + 16 * MB;               // 8MB  fp8 codebook
    uint32_t* pk = (uint32_t*)(cq + 8 * MB);   // 12.6MB packed keys

    vq_prep<<<dim3(24576), 256, 0, stream>>>(x, cb, xq, cq);
    vq_gemm_top3<<<dim3(T_TOKENS / BN, N_CODES / BM), 256, 0, stream>>>(cq, xq, pk);
    vq_reduce_gather<<<dim3(T_TOKENS), 256, 0, stream>>>(pk, x, cb, out);
  } else {
    vq_naive<<<dim3(T_TOKENS), 256, 0, stream>>>(x, cb, out);
  }
}